// Round 8
// baseline (31190.649 us; speedup 1.0000x reference)
//
#include <hip/hip_runtime.h>
#include <math.h>

#define N_ROWS   16384
#define DIM      512
#define DQV      128          // DIM/4 float4s per row
#define K_CODES  8192
#define NSPLIT   2
#define KHALF    (K_CODES / NSPLIT)
#define BM       128          // rows per block = 16 waves x 8 rows
#define RPW      8            // rows per wave
#define BK       512          // codes per strip
#define BD       32           // d-chunk per tile (deep tile: amortize barriers)
#define DCS      (DIM / BD)   // 16 d-chunks per strip
#define NSTRIP   (KHALF / BK) // 8 strips per half
#define THREADS  1024         // 16 waves
#define EPI_BM   64

#define OUT_LOSS 8388608
#define OUT_PERP 8388609
#define OUT_IDX  8388610

// workspace layout (bytes)
#define WS_XX    0            // 16384 f32
#define WS_BV0   65536        // 16384 f32
#define WS_BI0   131072       // 16384 i32
#define WS_BV1   196608       // 16384 f32
#define WS_BI1   262144       // 16384 i32
#define WS_LOSS  327680       // double
#define WS_MAXI  327688       // int

__global__ void init_ws(double* ws_loss, int* ws_maxidx) {
    *ws_loss = 0.0;
    *ws_maxidx = 0;
}

// ---- numpy pairwise-sum emulation of xx[n] = np.sum(flat**2, axis=1) ----
__device__ __forceinline__ float p128_sq(const float4* p) {
    float4 q0 = p[0], q1 = p[1];
    float r0 = __fmul_rn(q0.x, q0.x), r1 = __fmul_rn(q0.y, q0.y);
    float r2 = __fmul_rn(q0.z, q0.z), r3 = __fmul_rn(q0.w, q0.w);
    float r4 = __fmul_rn(q1.x, q1.x), r5 = __fmul_rn(q1.y, q1.y);
    float r6 = __fmul_rn(q1.z, q1.z), r7 = __fmul_rn(q1.w, q1.w);
    #pragma unroll
    for (int t = 1; t < 16; ++t) {
        q0 = p[2 * t]; q1 = p[2 * t + 1];
        r0 = __fadd_rn(r0, __fmul_rn(q0.x, q0.x));
        r1 = __fadd_rn(r1, __fmul_rn(q0.y, q0.y));
        r2 = __fadd_rn(r2, __fmul_rn(q0.z, q0.z));
        r3 = __fadd_rn(r3, __fmul_rn(q0.w, q0.w));
        r4 = __fadd_rn(r4, __fmul_rn(q1.x, q1.x));
        r5 = __fadd_rn(r5, __fmul_rn(q1.y, q1.y));
        r6 = __fadd_rn(r6, __fmul_rn(q1.z, q1.z));
        r7 = __fadd_rn(r7, __fmul_rn(q1.w, q1.w));
    }
    return __fadd_rn(__fadd_rn(__fadd_rn(r0, r1), __fadd_rn(r2, r3)),
                     __fadd_rn(__fadd_rn(r4, r5), __fadd_rn(r6, r7)));
}

__global__ __launch_bounds__(256) void xx_kernel(const float4* __restrict__ x4,
                                                 float* __restrict__ xx) {
    int row = blockIdx.x * 256 + threadIdx.x;
    const float4* p = x4 + (size_t)row * DQV;
    float a = p128_sq(p);
    float b = p128_sq(p + 32);
    float c = p128_sq(p + 64);
    float d = p128_sq(p + 96);
    xx[row] = __fadd_rn(__fadd_rn(a, b), __fadd_rn(c, d));
}

// transpose x [16384][512] -> xt [512][16384], staged in d_out (rewritten by vq_epi)
__global__ __launch_bounds__(256) void xt_kernel(const float* __restrict__ x,
                                                 float* __restrict__ xt) {
    __shared__ float t[64][65];
    const int bn = blockIdx.x;            // n tile (64 rows)
    const int bd = blockIdx.y;            // d tile (64 dims)
    const int tx = threadIdx.x & 15;
    const int ty = threadIdx.x >> 4;
    #pragma unroll
    for (int i = 0; i < 4; ++i) {
        int nl = 16 * i + ty;
        float4 v = *(const float4*)(x + (size_t)(bn * 64 + nl) * DIM + bd * 64 + 4 * tx);
        t[4 * tx + 0][nl] = v.x;
        t[4 * tx + 1][nl] = v.y;
        t[4 * tx + 2][nl] = v.z;
        t[4 * tx + 3][nl] = v.w;
    }
    __syncthreads();
    #pragma unroll
    for (int i = 0; i < 4; ++i) {
        int dl = 16 * i + ty;
        float4 w;
        w.x = t[dl][4 * tx + 0];
        w.y = t[dl][4 * tx + 1];
        w.z = t[dl][4 * tx + 2];
        w.w = t[dl][4 * tx + 3];
        *(float4*)(xt + (size_t)(bd * 64 + dl) * N_ROWS + bn * 64 + 4 * tx) = w;
    }
}

// Stage one (E,X) tile into LDS buffer b. eb = &Et[b][(q*16)*BK + cc],
// 16 scalar stores stride BK apart (stride-1 across threads -> conflict-free);
// xsb = one float4 store.
__device__ __forceinline__ void stage_tile(float* __restrict__ eb,
                                           float4 pe0, float4 pe1,
                                           float4 pe2, float4 pe3,
                                           float4* __restrict__ xsb, float4 px) {
    eb[0 * BK]  = pe0.x; eb[1 * BK]  = pe0.y; eb[2 * BK]  = pe0.z; eb[3 * BK]  = pe0.w;
    eb[4 * BK]  = pe1.x; eb[5 * BK]  = pe1.y; eb[6 * BK]  = pe1.z; eb[7 * BK]  = pe1.w;
    eb[8 * BK]  = pe2.x; eb[9 * BK]  = pe2.y; eb[10 * BK] = pe2.z; eb[11 * BK] = pe2.w;
    eb[12 * BK] = pe3.x; eb[13 * BK] = pe3.y; eb[14 * BK] = pe3.z; eb[15 * BK] = pe3.w;
    *xsb = px;
}

// One 32-dim tile of FMAs, all operands from LDS (broadcast X, per-lane E).
// Accumulation order per (row,code): dd ascending — identical to the verified
// round-3 kernel (dims 0..511 sequential across dc tiles) -> bit-exact.
__device__ __forceinline__ void fma_tile(const float* __restrict__ etb,
                                         const float* __restrict__ xtb,
                                         float acc[RPW][8]) {
    #pragma unroll
    for (int dd = 0; dd < BD; ++dd) {
        float4 xa = *(const float4*)(xtb + dd * BM);
        float4 xb = *(const float4*)(xtb + dd * BM + 4);
        float4 e0 = *(const float4*)(etb + dd * BK);
        float4 e1 = *(const float4*)(etb + dd * BK + 256);
        float xs[8] = {xa.x, xa.y, xa.z, xa.w, xb.x, xb.y, xb.z, xb.w};
        float ev[8] = {e0.x, e0.y, e0.z, e0.w, e1.x, e1.y, e1.z, e1.w};
        #pragma unroll
        for (int i = 0; i < RPW; ++i)
            #pragma unroll
            for (int j = 0; j < 8; ++j)
                acc[i][j] = __fmaf_rn(xs[i], ev[j], acc[i][j]);
    }
}

// Round-8 structure: round-3 operand roles (8 rows/wave broadcast X, 8
// codes/lane E) but BD=32 deep tiles filling all 160 KB LDS:
//   Et[2][32*512] = 128 KB, Xs[2][32*128] = 32 KB -> 163840 B exactly
//   (round 7 proved this size launches).
// Why: round-7 post-mortem showed the binding constraints are (a) per-CU LDS
// delivery (~12 cyc/ds_read_b128) and (b) ~4K cyc of per-barrier overhead.
// Round 7 halved FMA/iter -> LDS+overhead bound (2470 us). Round 3 balanced
// FMA vs LDS but paid 520 barriers + s_load/lgkmcnt serialization (1875 us).
// BD=32: barriers 520 -> 136, FMA/iter x4 (16.4K cyc/CU vs LDS ~12-18K),
// X via LDS broadcast (no SMEM in the loop). Next-tile global loads issue
// AFTER the FMA phase: pe/px live ~600 cyc instead of 16K (round-4 lesson:
// staging-reg pressure through long phases is what bites; exposed latency
// costs only ~35 us total).
// Dead levers (proven): waves_per_eu / launch_bounds(,4) / LDS-forced
// occupancy all leave VGPR_Count=64 — allocator targets 64 unconditionally.
__global__ __launch_bounds__(THREADS)
void vq_main(const float* __restrict__ xt,
             const float* __restrict__ emb,
             const float* __restrict__ xx,
             float* __restrict__ bv0,
             int* __restrict__ bi0,
             float* __restrict__ bv1,
             int* __restrict__ bi1) {
    __shared__ float Et[2][BD * BK];      // 128 KB: E tile [dd][code], dbuf
    __shared__ float Xs[2][BD * BM];      // 32 KB:  X tile [dd][row],  dbuf

    const int tid  = threadIdx.x;
    const int lane = tid & 63;
    const int wv   = tid >> 6;            // 0..15
    const int wvu  = __builtin_amdgcn_readfirstlane(wv);
    const int rt   = blockIdx.x >> 1;     // row tile
    const int h    = blockIdx.x & 1;      // code half
    const int r0   = rt * BM;
    const int kb   = h * KHALF;
    const int rl   = wvu << 3;            // wave's first local row (uniform)
    const int rwu  = r0 + rl;             // wave's first global row

    const float4* emb4 = (const float4*)emb;
    const float4* xt4  = (const float4*)xt;

    // E-stage mapping: cc = code within strip, q = 16-dim half of the 32-dim tile
    const int cc = tid & 511;
    const int q  = tid >> 9;              // 0/1
    // X-stage mapping: xd = dim within tile (0..31), xq = float4 row index (0..31)
    const int xd = tid >> 5;
    const int xq = tid & 31;

    float bestv[RPW];
    int   besti[RPW];
    #pragma unroll
    for (int i = 0; i < RPW; ++i) { bestv[i] = 3.402823466e38f; besti[i] = 0; }

    // initial prefetch: strip 0, tile 0 (dims 0..31)
    float4 pe0, pe1, pe2, pe3, px;
    {
        const float4* ep = emb4 + (size_t)(kb + cc) * DQV + q * 4;
        pe0 = ep[0]; pe1 = ep[1]; pe2 = ep[2]; pe3 = ep[3];
        px  = xt4[(size_t)xd * (N_ROWS / 4) + (r0 >> 2) + xq];
    }

    for (int kc = 0; kc < NSTRIP; ++kc) {
        const int k0 = kb + kc * BK;

        float acc[RPW][8];
        #pragma unroll
        for (int i = 0; i < RPW; ++i)
            #pragma unroll
            for (int j = 0; j < 8; ++j) acc[i][j] = 0.0f;

        __syncthreads();   // prior strip finished all reads of buf0
        stage_tile(&Et[0][(q * 16) * BK + cc], pe0, pe1, pe2, pe3,
                   (float4*)(Xs[0]) + xd * 32 + xq, px);

        for (int dc = 0; dc < DCS; ++dc) {
            const int buf = dc & 1;
            __syncthreads();   // buf tile visible; other buf's readers done

            // compute current tile (pure LDS: broadcast X + per-lane E)
            fma_tile(&Et[buf][4 * lane], &Xs[buf][rl], acc);

            // late prefetch of next tile (short pe/px live range)
            {
                int nk0, ndb;
                if (dc < DCS - 1) { nk0 = k0; ndb = (dc + 1) * BD; }
                else { nk0 = (kc < NSTRIP - 1) ? k0 + BK : kb; ndb = 0; }
                const float4* ep = emb4 + (size_t)(nk0 + cc) * DQV + (ndb >> 2) + q * 4;
                pe0 = ep[0]; pe1 = ep[1]; pe2 = ep[2]; pe3 = ep[3];
                px  = xt4[(size_t)(ndb + xd) * (N_ROWS / 4) + (r0 >> 2) + xq];
            }

            // store next tile into the other buffer (its readers passed the
            // barrier at the top of this iteration)
            if (dc < DCS - 1) {
                const int nb = buf ^ 1;
                stage_tile(&Et[nb][(q * 16) * BK + cc], pe0, pe1, pe2, pe3,
                           (float4*)(Xs[nb]) + xd * 32 + xq, px);
            }
        }

        // strip epilogue: s = fl(xx - 2*dot); lane-local running argmin.
        // Lane codes ascend (4l..4l+3 then 256+4l..+3); strips ascend; strict <
        // keeps lowest code per fp32 ulp-bin = numpy first-min.
        #pragma unroll
        for (int i = 0; i < RPW; ++i) {
            float xr_n = xx[rwu + i];
            #pragma unroll
            for (int j2 = 0; j2 < 2; ++j2) {
                #pragma unroll
                for (int t = 0; t < 4; ++t) {
                    float s = __fmaf_rn(-2.0f, acc[i][4 * j2 + t], xr_n);
                    int code = k0 + 256 * j2 + 4 * lane + t;
                    if (s < bestv[i]) { bestv[i] = s; besti[i] = code; }
                }
            }
        }
    }

    // ---- cross-lane argmin (wave shuffle butterfly, once per kernel) ----
    #pragma unroll
    for (int i = 0; i < RPW; ++i) {
        float v  = bestv[i];
        int  idx = besti[i];
        #pragma unroll
        for (int off = 32; off > 0; off >>= 1) {
            float vv = __shfl_down(v, off);
            int   ii = __shfl_down(idx, off);
            if (vv < v || (vv == v && ii < idx)) { v = vv; idx = ii; }
        }
        if (lane == 0) {
            if (h == 0) { bv0[rwu + i] = v; bi0[rwu + i] = idx; }
            else        { bv1[rwu + i] = v; bi1[rwu + i] = idx; }
        }
    }
}

// merge halves + gather + straight-through + loss
__global__ __launch_bounds__(256) void vq_epi(const float* __restrict__ x,
                                              const float* __restrict__ emb,
                                              const float* __restrict__ bv0,
                                              const int* __restrict__ bi0,
                                              const float* __restrict__ bv1,
                                              const int* __restrict__ bi1,
                                              float* __restrict__ out,
                                              double* __restrict__ ws_loss,
                                              int* __restrict__ ws_maxidx) {
    __shared__ int idxRow[EPI_BM];
    const int tid = threadIdx.x;
    const int r0  = blockIdx.x * EPI_BM;
    const float4* x4   = (const float4*)x;
    const float4* emb4 = (const float4*)emb;
    float4*       out4 = (float4*)out;

    if (tid < EPI_BM) {
        int row = r0 + tid;
        float v0 = bv0[row]; int i0 = bi0[row];
        float v1 = bv1[row]; int i1 = bi1[row];
        // half0 codes all < half1 codes: tie (v1==v0) keeps i0 = numpy first-min
        int idx = (v1 < v0) ? i1 : i0;
        idxRow[tid] = idx;
        out[OUT_IDX + row] = (float)idx;
        atomicMax(ws_maxidx, idx);
    }
    __syncthreads();

    double lsum = 0.0;
    for (int i = tid; i < EPI_BM * DQV; i += 256) {
        int row = i >> 7, dq = i & 127;
        int ki  = idxRow[row];
        float4 q  = emb4[(size_t)ki * DQV + dq];
        float4 xv = x4[(size_t)(r0 + row) * DQV + dq];
        float d0 = q.x - xv.x, d1 = q.y - xv.y, d2 = q.z - xv.z, d3 = q.w - xv.w;
        lsum += (double)d0 * (double)d0 + (double)d1 * (double)d1
              + (double)d2 * (double)d2 + (double)d3 * (double)d3;
        float4 o;
        o.x = xv.x + d0; o.y = xv.y + d1; o.z = xv.z + d2; o.w = xv.w + d3;
        out4[(size_t)(r0 + row) * DQV + dq] = o;
    }
    #pragma unroll
    for (int off = 32; off > 0; off >>= 1) lsum += __shfl_down(lsum, off);
    if ((tid & 63) == 0) atomicAdd(ws_loss, lsum);
}

__global__ void vq_final(const double* __restrict__ ws_loss,
                         const int* __restrict__ ws_maxidx,
                         float* __restrict__ out) {
    if (threadIdx.x == 0) {
        double mean = *ws_loss / (double)((size_t)N_ROWS * DIM);
        out[OUT_LOSS] = (float)(1.25 * mean);   // q_latent + 0.25*e_latent
        double L   = (double)(*ws_maxidx + 1);
        double avg = 1.0 / L;
        out[OUT_PERP] = (float)exp(-avg * log(avg + 1e-10));
    }
}

extern "C" void kernel_launch(void* const* d_in, const int* in_sizes, int n_in,
                              void* d_out, int out_size, void* d_ws, size_t ws_size,
                              hipStream_t stream) {
    const float* x   = (const float*)d_in[0];
    const float* emb = (const float*)d_in[1];
    float* out = (float*)d_out;

    char* ws = (char*)d_ws;
    float*  xx        = (float*)(ws + WS_XX);
    float*  bv0       = (float*)(ws + WS_BV0);
    int*    bi0       = (int*)  (ws + WS_BI0);
    float*  bv1       = (float*)(ws + WS_BV1);
    int*    bi1       = (int*)  (ws + WS_BI1);
    double* ws_loss   = (double*)(ws + WS_LOSS);
    int*    ws_maxidx = (int*)  (ws + WS_MAXI);

    // xt lives in d_out[0 .. 8388608) -- dead space until vq_epi rewrites it
    float* xt = out;

    hipLaunchKernelGGL(init_ws, dim3(1), dim3(1), 0, stream, ws_loss, ws_maxidx);
    hipLaunchKernelGGL(xx_kernel, dim3(N_ROWS / 256), dim3(256), 0, stream,
                       (const float4*)x, xx);
    hipLaunchKernelGGL(xt_kernel, dim3(N_ROWS / 64, DIM / 64), dim3(256), 0, stream,
                       x, xt);
    hipLaunchKernelGGL(vq_main, dim3((N_ROWS / BM) * NSPLIT), dim3(THREADS), 0, stream,
                       xt, emb, xx, bv0, bi0, bv1, bi1);
    hipLaunchKernelGGL(vq_epi, dim3(N_ROWS / EPI_BM), dim3(256), 0, stream,
                       x, emb, bv0, bi0, bv1, bi1, out, ws_loss, ws_maxidx);
    hipLaunchKernelGGL(vq_final, dim3(1), dim3(64), 0, stream,
                       ws_loss, ws_maxidx, out);
}

// Round 9
// 1791.360 us; speedup vs baseline: 17.4117x; 17.4117x over previous
//
#include <hip/hip_runtime.h>
#include <math.h>

#define N_ROWS   16384
#define DIM      512
#define DQV      128          // DIM/4 float4s per row
#define K_CODES  8192
#define NSPLIT   2
#define KHALF    (K_CODES / NSPLIT)
#define BM       64           // rows per block = 8 waves x 8 rows
#define RPW      8            // rows per wave
#define BK       512          // codes per strip
#define BD       8            // d-chunk per tile
#define DCS      (DIM / BD)   // 64 d-chunks
#define NSTRIP   (KHALF / BK) // 8 strips per half
#define THREADS  512          // 8 waves: min 2 waves/EU -> 256-VGPR cap
#define EPI_BM   64

#define OUT_LOSS 8388608
#define OUT_PERP 8388609
#define OUT_IDX  8388610

// workspace layout (bytes)
#define WS_XX    0            // 16384 f32
#define WS_BV0   65536        // 16384 f32
#define WS_BI0   131072       // 16384 i32
#define WS_BV1   196608       // 16384 f32
#define WS_BI1   262144       // 16384 i32
#define WS_LOSS  327680       // double
#define WS_MAXI  327688       // int

__global__ void init_ws(double* ws_loss, int* ws_maxidx) {
    *ws_loss = 0.0;
    *ws_maxidx = 0;
}

// ---- numpy pairwise-sum emulation of xx[n] = np.sum(flat**2, axis=1) ----
__device__ __forceinline__ float p128_sq(const float4* p) {
    float4 q0 = p[0], q1 = p[1];
    float r0 = __fmul_rn(q0.x, q0.x), r1 = __fmul_rn(q0.y, q0.y);
    float r2 = __fmul_rn(q0.z, q0.z), r3 = __fmul_rn(q0.w, q0.w);
    float r4 = __fmul_rn(q1.x, q1.x), r5 = __fmul_rn(q1.y, q1.y);
    float r6 = __fmul_rn(q1.z, q1.z), r7 = __fmul_rn(q1.w, q1.w);
    #pragma unroll
    for (int t = 1; t < 16; ++t) {
        q0 = p[2 * t]; q1 = p[2 * t + 1];
        r0 = __fadd_rn(r0, __fmul_rn(q0.x, q0.x));
        r1 = __fadd_rn(r1, __fmul_rn(q0.y, q0.y));
        r2 = __fadd_rn(r2, __fmul_rn(q0.z, q0.z));
        r3 = __fadd_rn(r3, __fmul_rn(q0.w, q0.w));
        r4 = __fadd_rn(r4, __fmul_rn(q1.x, q1.x));
        r5 = __fadd_rn(r5, __fmul_rn(q1.y, q1.y));
        r6 = __fadd_rn(r6, __fmul_rn(q1.z, q1.z));
        r7 = __fadd_rn(r7, __fmul_rn(q1.w, q1.w));
    }
    return __fadd_rn(__fadd_rn(__fadd_rn(r0, r1), __fadd_rn(r2, r3)),
                     __fadd_rn(__fadd_rn(r4, r5), __fadd_rn(r6, r7)));
}

__global__ __launch_bounds__(256) void xx_kernel(const float4* __restrict__ x4,
                                                 float* __restrict__ xx) {
    int row = blockIdx.x * 256 + threadIdx.x;
    const float4* p = x4 + (size_t)row * DQV;
    float a = p128_sq(p);
    float b = p128_sq(p + 32);
    float c = p128_sq(p + 64);
    float d = p128_sq(p + 96);
    xx[row] = __fadd_rn(__fadd_rn(a, b), __fadd_rn(c, d));
}

// transpose x [16384][512] -> xt [512][16384], staged in d_out (rewritten by vq_epi)
__global__ __launch_bounds__(256) void xt_kernel(const float* __restrict__ x,
                                                 float* __restrict__ xt) {
    __shared__ float t[64][65];
    const int bn = blockIdx.x;            // n tile (64 rows)
    const int bd = blockIdx.y;            // d tile (64 dims)
    const int tx = threadIdx.x & 15;
    const int ty = threadIdx.x >> 4;
    #pragma unroll
    for (int i = 0; i < 4; ++i) {
        int nl = 16 * i + ty;
        float4 v = *(const float4*)(x + (size_t)(bn * 64 + nl) * DIM + bd * 64 + 4 * tx);
        t[4 * tx + 0][nl] = v.x;
        t[4 * tx + 1][nl] = v.y;
        t[4 * tx + 2][nl] = v.z;
        t[4 * tx + 3][nl] = v.w;
    }
    __syncthreads();
    #pragma unroll
    for (int i = 0; i < 4; ++i) {
        int dl = 16 * i + ty;
        float4 w;
        w.x = t[dl][4 * tx + 0];
        w.y = t[dl][4 * tx + 1];
        w.z = t[dl][4 * tx + 2];
        w.w = t[dl][4 * tx + 3];
        *(float4*)(xt + (size_t)(bd * 64 + dl) * N_ROWS + bn * 64 + 4 * tx) = w;
    }
}

// Round-9 structure: wg=512 (8 waves x 8 rows), X resident in LDS, Et dbuf.
//   Xs[512][64] = 128 KB (staged once) + Et[2][8*512] = 32 KB -> 163840 B
//   exactly (round 7 proved launchable). 1 block/CU, 2 waves/SIMD.
// WHY wg=512: round-8's 72 GB WRITE_SIZE (275 KB/thread scratch, 31 ms)
// PROVED the spill mechanism; across rounds 0-7 the allocator pinned 64
// arch-VGPRs at wg=1024 regardless of waves_per_eu / launch_bounds(,4) /
// 160KB-LDS-forced occupancy. The 64-pin has only been observed at wg=1024;
// 256-thread kernels (guide's m97 GEMM) get 164 VGPRs. wg=512 + (512,2)
// permits 256 VGPRs/wave; live set ~114 (acc 64 + operands + pe + addr)
// should fit spill-free. Inner loop is pure LDS (2 broadcast X b128 +
// 2 per-lane E b128 + 64 FMA per dd): no SMEM in loop, FMA wall (2048
// clk/dc/SIMD) > LDS wall (~1536 clk/dc/CU). FMA order per (row,code)
// identical to round 3 (dims ascending 0..511) -> absmax 0.0.
__global__ __launch_bounds__(THREADS, 2)
void vq_main(const float* __restrict__ xt,
             const float* __restrict__ emb,
             const float* __restrict__ xx,
             float* __restrict__ bv0,
             int* __restrict__ bi0,
             float* __restrict__ bv1,
             int* __restrict__ bi1) {
    __shared__ float Xs[DIM * BM];        // 128 KB: [d][r_local], whole-kernel resident
    __shared__ float Et[2][BD * BK];      // 32 KB:  E tile [dd][code], double-buffered

    const int tid  = threadIdx.x;
    const int lane = tid & 63;
    const int wv   = tid >> 6;            // 0..7
    const int wvu  = __builtin_amdgcn_readfirstlane(wv);
    const int rt   = blockIdx.x >> 1;     // row tile
    const int h    = blockIdx.x & 1;      // code half
    const int r0   = rt * BM;
    const int kb   = h * KHALF;
    const int rl   = wvu << 3;            // wave's first local row (uniform)
    const int rwu  = r0 + rl;             // wave's first global row

    const float4* emb4 = (const float4*)emb;
    const float4* xt4  = (const float4*)xt;
    const int cc = tid;                   // staged code id within strip (0..511)

    // ---- stage X tile once: Xs[d*64 + r] = xt[d][r0 + r] ----
    {
        float4* xs4 = (float4*)Xs;
        #pragma unroll
        for (int it = 0; it < 16; ++it) {
            int i  = it * THREADS + tid;  // 0..8191 float4s
            int d  = i >> 4;              // 16 float4 per d-row
            int rq = i & 15;
            xs4[i] = xt4[(size_t)d * (N_ROWS / 4) + (r0 >> 2) + rq];
        }
    }
    // visibility covered by the strip-top __syncthreads below

    float bestv[RPW];
    int   besti[RPW];
    #pragma unroll
    for (int i = 0; i < RPW; ++i) { bestv[i] = 3.402823466e38f; besti[i] = 0; }

    // initial prefetch: strip 0, dc 0 (dims 0..7 of code kb+cc)
    float4 pe0, pe1;
    {
        const float4* ep = emb4 + (size_t)(kb + cc) * DQV;
        pe0 = ep[0]; pe1 = ep[1];
    }

    for (int kc = 0; kc < NSTRIP; ++kc) {
        const int k0 = kb + kc * BK;

        float acc[RPW][8];
        #pragma unroll
        for (int i = 0; i < RPW; ++i)
            #pragma unroll
            for (int j = 0; j < 8; ++j) acc[i][j] = 0.0f;

        __syncthreads();   // prior strip finished all reads of buf0 (and Xs staged)
        {
            Et[0][0 * BK + cc] = pe0.x; Et[0][1 * BK + cc] = pe0.y;
            Et[0][2 * BK + cc] = pe0.z; Et[0][3 * BK + cc] = pe0.w;
            Et[0][4 * BK + cc] = pe1.x; Et[0][5 * BK + cc] = pe1.y;
            Et[0][6 * BK + cc] = pe1.z; Et[0][7 * BK + cc] = pe1.w;
        }

        for (int dc = 0; dc < DCS; ++dc) {
            const int buf = dc & 1;
            __syncthreads();   // buf ready; other buf's readers done

            // prefetch next E tile (next dc, or next strip's dc=0)
            {
                int nk0, ndq;
                if (dc < DCS - 1) { nk0 = k0; ndq = 2 * (dc + 1); }
                else { nk0 = (kc < NSTRIP - 1) ? k0 + BK : kb; ndq = 0; }
                const float4* ep = emb4 + (size_t)(nk0 + cc) * DQV + ndq;
                pe0 = ep[0]; pe1 = ep[1];
            }

            const int dbase = dc * BD;
            // k-sequential fp32 FMA chain per (row,code) — order identical to
            // round 3 (dims 0..511 sequential) -> bit-exact vs reference
            #pragma unroll
            for (int dd = 0; dd < BD; ++dd) {
                // X: 8 wave-uniform floats, 2 broadcast ds_read_b128
                float4 xa = *(const float4*)(&Xs[(dbase + dd) * BM + rl]);
                float4 xb = *(const float4*)(&Xs[(dbase + dd) * BM + rl + 4]);
                const float* ep = &Et[buf][dd * BK + 4 * lane];
                float4 e0 = *(const float4*)(ep);
                float4 e1 = *(const float4*)(ep + 256);
                float xs[RPW] = {xa.x, xa.y, xa.z, xa.w, xb.x, xb.y, xb.z, xb.w};
                float ev[8] = {e0.x, e0.y, e0.z, e0.w, e1.x, e1.y, e1.z, e1.w};
                #pragma unroll
                for (int i = 0; i < RPW; ++i)
                    #pragma unroll
                    for (int j = 0; j < 8; ++j)
                        acc[i][j] = __fmaf_rn(xs[i], ev[j], acc[i][j]);
            }

            // store next tile into the other buffer (its readers passed the
            // barrier at the top of this iteration)
            if (dc < DCS - 1) {
                const int nb = buf ^ 1;
                Et[nb][0 * BK + cc] = pe0.x; Et[nb][1 * BK + cc] = pe0.y;
                Et[nb][2 * BK + cc] = pe0.z; Et[nb][3 * BK + cc] = pe0.w;
                Et[nb][4 * BK + cc] = pe1.x; Et[nb][5 * BK + cc] = pe1.y;
                Et[nb][6 * BK + cc] = pe1.z; Et[nb][7 * BK + cc] = pe1.w;
            }
        }

        // strip epilogue: s = fl(xx - 2*dot); lane-local running argmin.
        // Lane codes ascend (4l..4l+3 then 256+4l..+3); strips ascend; strict <
        // keeps lowest code per fp32 ulp-bin = numpy first-min.
        #pragma unroll
        for (int i = 0; i < RPW; ++i) {
            float xr_n = xx[rwu + i];
            #pragma unroll
            for (int j2 = 0; j2 < 2; ++j2) {
                #pragma unroll
                for (int t = 0; t < 4; ++t) {
                    float s = __fmaf_rn(-2.0f, acc[i][4 * j2 + t], xr_n);
                    int code = k0 + 256 * j2 + 4 * lane + t;
                    if (s < bestv[i]) { bestv[i] = s; besti[i] = code; }
                }
            }
        }
    }

    // ---- cross-lane argmin (wave shuffle butterfly, once per kernel) ----
    #pragma unroll
    for (int i = 0; i < RPW; ++i) {
        float v  = bestv[i];
        int  idx = besti[i];
        #pragma unroll
        for (int off = 32; off > 0; off >>= 1) {
            float vv = __shfl_down(v, off);
            int   ii = __shfl_down(idx, off);
            if (vv < v || (vv == v && ii < idx)) { v = vv; idx = ii; }
        }
        if (lane == 0) {
            if (h == 0) { bv0[rwu + i] = v; bi0[rwu + i] = idx; }
            else        { bv1[rwu + i] = v; bi1[rwu + i] = idx; }
        }
    }
}

// merge halves + gather + straight-through + loss
__global__ __launch_bounds__(256) void vq_epi(const float* __restrict__ x,
                                              const float* __restrict__ emb,
                                              const float* __restrict__ bv0,
                                              const int* __restrict__ bi0,
                                              const float* __restrict__ bv1,
                                              const int* __restrict__ bi1,
                                              float* __restrict__ out,
                                              double* __restrict__ ws_loss,
                                              int* __restrict__ ws_maxidx) {
    __shared__ int idxRow[EPI_BM];
    const int tid = threadIdx.x;
    const int r0  = blockIdx.x * EPI_BM;
    const float4* x4   = (const float4*)x;
    const float4* emb4 = (const float4*)emb;
    float4*       out4 = (float4*)out;

    if (tid < EPI_BM) {
        int row = r0 + tid;
        float v0 = bv0[row]; int i0 = bi0[row];
        float v1 = bv1[row]; int i1 = bi1[row];
        // half0 codes all < half1 codes: tie (v1==v0) keeps i0 = numpy first-min
        int idx = (v1 < v0) ? i1 : i0;
        idxRow[tid] = idx;
        out[OUT_IDX + row] = (float)idx;
        atomicMax(ws_maxidx, idx);
    }
    __syncthreads();

    double lsum = 0.0;
    for (int i = tid; i < EPI_BM * DQV; i += 256) {
        int row = i >> 7, dq = i & 127;
        int ki  = idxRow[row];
        float4 q  = emb4[(size_t)ki * DQV + dq];
        float4 xv = x4[(size_t)(r0 + row) * DQV + dq];
        float d0 = q.x - xv.x, d1 = q.y - xv.y, d2 = q.z - xv.z, d3 = q.w - xv.w;
        lsum += (double)d0 * (double)d0 + (double)d1 * (double)d1
              + (double)d2 * (double)d2 + (double)d3 * (double)d3;
        float4 o;
        o.x = xv.x + d0; o.y = xv.y + d1; o.z = xv.z + d2; o.w = xv.w + d3;
        out4[(size_t)(r0 + row) * DQV + dq] = o;
    }
    #pragma unroll
    for (int off = 32; off > 0; off >>= 1) lsum += __shfl_down(lsum, off);
    if ((tid & 63) == 0) atomicAdd(ws_loss, lsum);
}

__global__ void vq_final(const double* __restrict__ ws_loss,
                         const int* __restrict__ ws_maxidx,
                         float* __restrict__ out) {
    if (threadIdx.x == 0) {
        double mean = *ws_loss / (double)((size_t)N_ROWS * DIM);
        out[OUT_LOSS] = (float)(1.25 * mean);   // q_latent + 0.25*e_latent
        double L   = (double)(*ws_maxidx + 1);
        double avg = 1.0 / L;
        out[OUT_PERP] = (float)exp(-avg * log(avg + 1e-10));
    }
}

extern "C" void kernel_launch(void* const* d_in, const int* in_sizes, int n_in,
                              void* d_out, int out_size, void* d_ws, size_t ws_size,
                              hipStream_t stream) {
    const float* x   = (const float*)d_in[0];
    const float* emb = (const float*)d_in[1];
    float* out = (float*)d_out;

    char* ws = (char*)d_ws;
    float*  xx        = (float*)(ws + WS_XX);
    float*  bv0       = (float*)(ws + WS_BV0);
    int*    bi0       = (int*)  (ws + WS_BI0);
    float*  bv1       = (float*)(ws + WS_BV1);
    int*    bi1       = (int*)  (ws + WS_BI1);
    double* ws_loss   = (double*)(ws + WS_LOSS);
    int*    ws_maxidx = (int*)  (ws + WS_MAXI);

    // xt lives in d_out[0 .. 8388608) -- dead space until vq_epi rewrites it
    float* xt = out;

    hipLaunchKernelGGL(init_ws, dim3(1), dim3(1), 0, stream, ws_loss, ws_maxidx);
    hipLaunchKernelGGL(xx_kernel, dim3(N_ROWS / 256), dim3(256), 0, stream,
                       (const float4*)x, xx);
    hipLaunchKernelGGL(xt_kernel, dim3(N_ROWS / 64, DIM / 64), dim3(256), 0, stream,
                       x, xt);
    hipLaunchKernelGGL(vq_main, dim3((N_ROWS / BM) * NSPLIT), dim3(THREADS), 0, stream,
                       xt, emb, xx, bv0, bi0, bv1, bi1);
    hipLaunchKernelGGL(vq_epi, dim3(N_ROWS / EPI_BM), dim3(256), 0, stream,
                       x, emb, bv0, bi0, bv1, bi1, out, ws_loss, ws_maxidx);
    hipLaunchKernelGGL(vq_final, dim3(1), dim3(64), 0, stream,
                       ws_loss, ws_maxidx, out);
}